// Round 1
// 196.061 us; speedup vs baseline: 1.1044x; 1.1044x over previous
//
#include <hip/hip_runtime.h>

typedef __attribute__((ext_vector_type(8))) short short8;
typedef __attribute__((ext_vector_type(4))) float f32x4;
typedef __attribute__((ext_vector_type(16))) float f32x16;

__device__ __forceinline__ unsigned short f2bf(float f) {
  unsigned int u = __float_as_uint(f);
  u += 0x7fffu + ((u >> 16) & 1u);   // round-to-nearest-even
  return (unsigned short)(u >> 16);
}
__device__ __forceinline__ float bf2f(unsigned short h) {
  return __uint_as_float(((unsigned int)h) << 16);
}
// HW packed f32->bf16 (RNE): 1 instr replaces ~6-op manual pack (low=a, high=b)
__device__ __forceinline__ unsigned int cvtpk(float a, float b) {
  unsigned int r;
  asm("v_cvt_pk_bf16_f32 %0, %1, %2" : "=v"(r) : "v"(a), "v"(b));
  return r;
}
__device__ __forceinline__ float lo16f(unsigned int u) { return __uint_as_float(u << 16); }
__device__ __forceinline__ float hi16f(unsigned int u) { return __uint_as_float(u & 0xffff0000u); }
__device__ __forceinline__ short8 ld8(const unsigned short* p) {
  return *(const short8*)p;
}
__device__ __forceinline__ int swap23(int x) {  // swap bits 2<->3
  return (x & 0x13) | ((x & 4) << 1) | ((x & 8) >> 1);
}
#define MFMA(a, b, c) __builtin_amdgcn_mfma_f32_16x16x32_bf16((a), (b), (c), 0, 0, 0)
#define MFMA32(a, b, c) __builtin_amdgcn_mfma_f32_32x32x16_bf16((a), (b), (c), 0, 0, 0)
#define LOG2E 1.4426950408889634f

typedef const __attribute__((address_space(1))) unsigned int* gas_u32p;
typedef __attribute__((address_space(3))) unsigned int* las_u32p;

// ---------------------------------------------------------------------------
// Kernel 1: weight prep. Wcat^T hi/lo bf16 [192][256] (rows 0-31 Wq^T, 32-63
// Wk^T, 64-191 Wv^T), WoT bf16 [256][128].
// ---------------------------------------------------------------------------
__global__ void prep_weights(const float* __restrict__ Wq, const float* __restrict__ Wk,
                             const float* __restrict__ Wv, const float* __restrict__ Wo,
                             unsigned short* __restrict__ Wth, unsigned short* __restrict__ Wtl,
                             unsigned short* __restrict__ WoT) {
  int idx = blockIdx.x * 256 + threadIdx.x;
  if (idx < 192 * 256) {
    int o = idx >> 8, c = idx & 255;
    float w = (o < 32) ? Wq[c * 32 + o] : (o < 64) ? Wk[c * 32 + (o - 32)] : Wv[c * 128 + (o - 64)];
    unsigned short h = f2bf(w);
    Wth[idx] = h;
    Wtl[idx] = f2bf(w - bf2f(h));
  } else if (idx < 192 * 256 + 256 * 128) {
    int j = idx - 192 * 256;
    int c = j >> 7, d = j & 127;
    WoT[j] = f2bf(Wo[d * 256 + c]);
  }
}

// ---------------------------------------------------------------------------
// Kernel 2: QKV projection. 32 pixels/block. q pre-scaled by log2(e).
// K and V are written into ONE fused fragment-major buffer KVF so the flash
// kernel can stage each nt-tile with 24 contiguous 1KB global_load_lds bursts:
//   KVF[b*64+nt] : [0,2048)   kh frags  [kt(2)][step(2)][lane(64)][e(8)]
//                  [2048,4096) kl frags (same layout)
//                  [4096,12288) V frags [dt(4)][ks(4)][lane(64)][e(8)]
// K-fragment lane h*32+lam holds K[nt*64+kt*32+swap23(lam)][16step+8h+e]
// V-fragment lane h*32+lam holds V^T[32dt+lam][nt*64+16ks+8h+e].
// ---------------------------------------------------------------------------
__global__ __launch_bounds__(256) void proj_qkv(
    const float* __restrict__ x,
    const unsigned short* __restrict__ Wth, const unsigned short* __restrict__ Wtl,
    const float* __restrict__ bq, const float* __restrict__ bk, const float* __restrict__ bv,
    unsigned short* __restrict__ qh, unsigned short* __restrict__ qlo,
    unsigned short* __restrict__ KVF) {
  __shared__ unsigned short xsh[32][264];
  __shared__ unsigned short xsl[32][264];
  const int pix0 = blockIdx.x * 32;
  const int b = pix0 >> 12;
  const int nloc0 = pix0 & 4095;
  const int tid = threadIdx.x;

#pragma unroll
  for (int i = 0; i < 8; ++i) {
    int chunk = i * 256 + tid;
    int row = chunk >> 6;
    int c4 = (chunk & 63) * 4;
    float4 v = *(const float4*)(x + (size_t)(pix0 + row) * 256 + c4);
    unsigned int h01 = cvtpk(v.x, v.y), h23 = cvtpk(v.z, v.w);
    unsigned int l01 = cvtpk(v.x - lo16f(h01), v.y - hi16f(h01));
    unsigned int l23 = cvtpk(v.z - lo16f(h23), v.w - hi16f(h23));
    uint2 hp, lp;
    hp.x = h01; hp.y = h23;
    lp.x = l01; lp.y = l23;
    *(uint2*)&xsh[row][c4] = hp;
    *(uint2*)&xsl[row][c4] = lp;
  }
  __syncthreads();

  const int wave = tid >> 6, lane = tid & 63, l = lane & 15, qd = lane >> 4;
#pragma unroll
  for (int si = 0; si < 3; ++si) {
    const int sub = wave + si * 4;
    const int outc0 = sub * 16;
    if (si == 0) {  // q/k, split precision
      const int outc = outc0 + l;
      const float bias = (outc < 32) ? bq[outc] : bk[outc - 32];
      f32x4 acc[2];
      acc[0] = (f32x4){bias, bias, bias, bias};
      acc[1] = (f32x4){bias, bias, bias, bias};
#pragma unroll
      for (int kc = 0; kc < 8; ++kc) {
        short8 whf = ld8(Wth + (size_t)(outc0 + l) * 256 + kc * 32 + qd * 8);
        short8 wlf = ld8(Wtl + (size_t)(outc0 + l) * 256 + kc * 32 + qd * 8);
#pragma unroll
        for (int m = 0; m < 2; ++m) {
          short8 xhf = ld8(&xsh[m * 16 + l][kc * 32 + qd * 8]);
          short8 xlf = ld8(&xsl[m * 16 + l][kc * 32 + qd * 8]);
          acc[m] = MFMA(xlf, whf, acc[m]);
          acc[m] = MFMA(xhf, wlf, acc[m]);
          acc[m] = MFMA(xhf, whf, acc[m]);
        }
      }
      if (outc < 32) {  // q: layout unchanged
#pragma unroll
        for (int m = 0; m < 2; ++m)
#pragma unroll
          for (int r = 0; r < 4; ++r) {
            const size_t pixel = (size_t)pix0 + m * 16 + 4 * qd + r;
            float val = acc[m][r] * LOG2E;   // exp2-domain softmax
            unsigned int hp = cvtpk(val, val);
            float res = val - lo16f(hp);
            qh[pixel * 32 + outc] = (unsigned short)hp;
            qlo[pixel * 32 + outc] = (unsigned short)cvtpk(res, res);
          }
      } else {  // k: fragment-major with bit-permuted row position
        const int kd = outc - 32;
        const int step = kd >> 4, hh = (kd >> 3) & 1, e = kd & 7;
#pragma unroll
        for (int m = 0; m < 2; ++m)
#pragma unroll
          for (int r = 0; r < 4; ++r) {
            const int nl = nloc0 + m * 16 + 4 * qd + r;
            const int nt = nl >> 6, j = nl & 63, kt = j >> 5;
            const int lpos = swap23(j & 31);
            const size_t koff = (size_t)(b * 64 + nt) * 12288 +
                                (kt * 2 + step) * 512 + (hh * 32 + lpos) * 8 + e;
            float val = acc[m][r];
            unsigned int hp = cvtpk(val, val);
            float res = val - lo16f(hp);
            KVF[koff] = (unsigned short)hp;
            KVF[koff + 2048] = (unsigned short)cvtpk(res, res);
          }
      }
    } else {  // v, transposed, fragment-major output
      const int dv0 = outc0 - 64;
      const float b0 = bv[dv0 + 4 * qd + 0], b1 = bv[dv0 + 4 * qd + 1];
      const float b2 = bv[dv0 + 4 * qd + 2], b3 = bv[dv0 + 4 * qd + 3];
      f32x4 acc[2];
      acc[0] = (f32x4){b0, b1, b2, b3};
      acc[1] = (f32x4){b0, b1, b2, b3};
#pragma unroll
      for (int kc = 0; kc < 8; ++kc) {
        short8 whf = ld8(Wth + (size_t)(outc0 + l) * 256 + kc * 32 + qd * 8);
#pragma unroll
        for (int m = 0; m < 2; ++m) {
          short8 xhf = ld8(&xsh[m * 16 + l][kc * 32 + qd * 8]);
          acc[m] = MFMA(whf, xhf, acc[m]);  // D = Wv^T * x^T
        }
      }
#pragma unroll
      for (int m = 0; m < 2; ++m)
#pragma unroll
        for (int r = 0; r < 4; ++r) {
          const int dv = dv0 + 4 * qd + r;
          const int dt = dv >> 5, lam = dv & 31;
          const int nl = nloc0 + m * 16 + l;
          const int nt = nl >> 6, j = nl & 63;
          const int ks = j >> 4, hh = (j >> 3) & 1, e = j & 7;
          const size_t voff = (size_t)(b * 64 + nt) * 12288 + 4096 +
                              (dt * 4 + ks) * 512 + (hh * 32 + lam) * 8 + e;
          KVF[voff] = (unsigned short)cvtpk(acc[m][r], acc[m][r]);
        }
    }
  }
}

// ---------------------------------------------------------------------------
// Kernel 3: flash attention, 32x32 MFMA, unnormalized exp2 softmax (no max
// subtraction needed: |logit*log2e| < ~60, so p in [2^-60, 2^60] stays in
// f32/bf16 range; normalization in combine divides it out).
// R7: K/V tile (24KB, fragment-major => linear) staged ONCE per block into
// double-buffered LDS via global_load_lds width=16, shared by all 4 waves.
// Replaces 24KB/wave-iter of TA traffic with 24KB/block-iter + LDS reads
// (~2x pipe BW, ~120cyc latency), and frees the 64-VGPR vf block ->
// __launch_bounds__(256,3) = 3 waves/SIMD (LDS 2x24KB=48KB -> 3 blocks/CU).
// Split-K x3, 768 blocks (= exactly 3/CU, single balanced pass);
// batch = blockIdx&7 -> XCD L2 locality.
// ---------------------------------------------------------------------------
__device__ __forceinline__ void stage_kv(const unsigned short* __restrict__ src,
                                         unsigned short* dst, int wave, int lane) {
#pragma unroll
  for (int i = 0; i < 6; ++i) {
    const int c = wave * 6 + i;  // 24 x 1KB chunks, linear copy
    __builtin_amdgcn_global_load_lds(
        (gas_u32p)(const void*)(src + c * 512 + lane * 8),
        (las_u32p)(void*)(dst + c * 512), 16, 0, 0);
  }
}

__global__ __launch_bounds__(256, 3) void flash_attn(
    const unsigned short* __restrict__ qh, const unsigned short* __restrict__ qlo,
    const unsigned short* __restrict__ KVF, unsigned short* __restrict__ opart,
    float* __restrict__ lstat) {
  __shared__ unsigned short kv[2][12288];   // 2 x 24KB double buffer
  const int b = blockIdx.x & 7;
  const int r7 = blockIdx.x >> 3;      // 0..95
  const int tile = r7 & 31;            // 0..31
  const int split = r7 >> 5;           // 0..2
  const int wave = threadIdx.x >> 6;
  const int lane = threadIdx.x & 63;
  const int lam = lane & 31;           // query index within wave
  const int h = lane >> 5;             // half-wave
  const int m0 = tile * 128 + wave * 32;
  const int nt_begin = (split * 64 + 2) / 3;        // 0 / 22 / 43
  const int nt_end = ((split + 1) * 64 + 2) / 3;    // 22 / 43 / 64

  const unsigned short* qh_b = qh + (size_t)b * 4096 * 32;
  const unsigned short* ql_b = qlo + (size_t)b * 4096 * 32;
  const unsigned short* kv_b = KVF + (size_t)b * 64 * 12288;

  // Q B-frags (persistent): B[k=dim 16*step+8h+j][n=query lam]
  short8 qhf[2], qlf[2];
#pragma unroll
  for (int step = 0; step < 2; ++step) {
    size_t off = (size_t)(m0 + lam) * 32 + step * 16 + h * 8;
    qhf[step] = ld8(qh_b + off);
    qlf[step] = ld8(ql_b + off);
  }

  f32x16 acc[4];
#pragma unroll
  for (int dt = 0; dt < 4; ++dt)
#pragma unroll
    for (int e = 0; e < 16; ++e) acc[dt][e] = 0.f;
  float lr0 = 0.f, lr1 = 0.f;

  stage_kv(kv_b + (size_t)nt_begin * 12288, &kv[0][0], wave, lane);
  __syncthreads();

  int cur = 0;
#pragma unroll 1
  for (int it = nt_begin; it < nt_end; ++it) {
    if (it + 1 < nt_end)   // prefetch next tile into the other buffer
      stage_kv(kv_b + (size_t)(it + 1) * 12288, &kv[cur ^ 1][0], wave, lane);

    const unsigned short* cb = &kv[cur][0];
#pragma unroll
    for (int kt = 0; kt < 2; ++kt) {
      // ---- QK^T (split precision) ----
      f32x16 z;
#pragma unroll
      for (int e = 0; e < 16; ++e) z[e] = 0.f;
#pragma unroll
      for (int step = 0; step < 2; ++step) {
        short8 khf = *(const short8*)(cb + (kt * 2 + step) * 512 + lane * 8);
        short8 klf = *(const short8*)(cb + 2048 + (kt * 2 + step) * 512 + lane * 8);
        z = MFMA32(klf, qhf[step], z);   // k_lo * q_hi
        z = MFMA32(khf, qlf[step], z);   // k_hi * q_lo
        z = MFMA32(khf, qhf[step], z);   // k_hi * q_hi
      }
      // ---- exp2 + HW bf16 pack ----
      unsigned int pp[8];
#pragma unroll
      for (int g = 0; g < 8; ++g) {
        float p0 = __builtin_amdgcn_exp2f(z[2 * g]);
        float p1 = __builtin_amdgcn_exp2f(z[2 * g + 1]);
        lr0 += p0;
        lr1 += p1;
        pp[g] = cvtpk(p0, p1);
      }
      // ---- PV for this kt's two key slots: O^T += V^T * P^T ----
#pragma unroll
      for (int kss = 0; kss < 2; ++kss) {
        union { unsigned int u[4]; short8 v; } pf;
        pf.u[0] = pp[4 * kss + 0];
        pf.u[1] = pp[4 * kss + 1];
        pf.u[2] = pp[4 * kss + 2];
        pf.u[3] = pp[4 * kss + 3];
        const int ks = kt * 2 + kss;
#pragma unroll
        for (int dt = 0; dt < 4; ++dt) {
          short8 vfrag = *(const short8*)(cb + 4096 + (dt * 4 + ks) * 512 + lane * 8);
          acc[dt] = MFMA32(vfrag, pf.v, acc[dt]);
        }
      }
    }
    __syncthreads();   // next-buffer staging landed; all waves done with cur
    cur ^= 1;
  }

  // Epilogue: combine l across half-waves, store unnormalized partials.
  const float lrun = lr0 + lr1;
  const float ltot = lrun + __shfl_xor(lrun, 32);
  const int grow = b * 4096 + m0 + lam;
  if (h == 0) lstat[split * 32768 + grow] = ltot;
  const size_t obase = ((size_t)split * 32768 + grow) * 128;
#pragma unroll
  for (int dt = 0; dt < 4; ++dt)
#pragma unroll
    for (int g = 0; g < 8; ++g) {
      int r = 2 * g;
      int dv = dt * 32 + (r & 3) + 8 * (r >> 2) + 4 * h;
      *(unsigned int*)(opart + obase + dv) = cvtpk(acc[dt][r], acc[dt][r + 1]);
    }
}

// ---------------------------------------------------------------------------
// Kernel 3b: combine split-K partials (unnormalized: plain sum) -> ao (bf16).
// ---------------------------------------------------------------------------
__global__ __launch_bounds__(256) void combine_splits(
    const unsigned short* __restrict__ opart, const float* __restrict__ lstat,
    unsigned short* __restrict__ ao) {
  const int tid = threadIdx.x;
  const int row = blockIdx.x * 16 + (tid >> 4);
  const int col = (tid & 15) * 8;
  float den = lstat[row] + lstat[32768 + row] + lstat[65536 + row];
  float inv = 1.f / den;
  float o[8] = {0.f, 0.f, 0.f, 0.f, 0.f, 0.f, 0.f, 0.f};
#pragma unroll
  for (int s = 0; s < 3; ++s) {
    uint4 v = *(const uint4*)(opart + ((size_t)s * 32768 + row) * 128 + col);
    unsigned int uu[4] = {v.x, v.y, v.z, v.w};
#pragma unroll
    for (int j = 0; j < 4; ++j) {
      o[2 * j]     += bf2f((unsigned short)(uu[j] & 0xffff));
      o[2 * j + 1] += bf2f((unsigned short)(uu[j] >> 16));
    }
  }
  uint4 outv;
  outv.x = cvtpk(o[0] * inv, o[1] * inv);
  outv.y = cvtpk(o[2] * inv, o[3] * inv);
  outv.z = cvtpk(o[4] * inv, o[5] * inv);
  outv.w = cvtpk(o[6] * inv, o[7] * inv);
  *(uint4*)(ao + (size_t)row * 128 + col) = outv;
}

// ---------------------------------------------------------------------------
// Kernel 4: output projection + bias + residual. out = ao @ Wo + bo + x.
// ---------------------------------------------------------------------------
__global__ __launch_bounds__(256) void out_proj(
    const unsigned short* __restrict__ ao, const unsigned short* __restrict__ WoT,
    const float* __restrict__ bo, const float* __restrict__ x, float* __restrict__ out) {
  const int pix0 = blockIdx.x * 64;
  const int wave = threadIdx.x >> 6, lane = threadIdx.x & 63, l = lane & 15, qd = lane >> 4;
  const int base = pix0 + wave * 16;
  short8 af[4];
#pragma unroll
  for (int kc = 0; kc < 4; ++kc)
    af[kc] = ld8(ao + (size_t)(base + l) * 128 + kc * 32 + qd * 8);
#pragma unroll
  for (int sub = 0; sub < 16; ++sub) {
    const int c = sub * 16 + l;
    const float bias = bo[c];
    f32x4 acc = (f32x4){bias, bias, bias, bias};
#pragma unroll
    for (int kc = 0; kc < 4; ++kc) {
      short8 wf = ld8(WoT + (size_t)c * 128 + kc * 32 + qd * 8);
      acc = MFMA(af[kc], wf, acc);
    }
#pragma unroll
    for (int r = 0; r < 4; ++r) {
      const size_t pixel = (size_t)base + 4 * qd + r;
      out[pixel * 256 + c] = acc[r] + x[pixel * 256 + c];
    }
  }
}

// ---------------------------------------------------------------------------
extern "C" void kernel_launch(void* const* d_in, const int* in_sizes, int n_in,
                              void* d_out, int out_size, void* d_ws, size_t ws_size,
                              hipStream_t stream) {
  const float* x  = (const float*)d_in[0];
  const float* Wq = (const float*)d_in[1];
  const float* bq = (const float*)d_in[2];
  const float* Wk = (const float*)d_in[3];
  const float* bk = (const float*)d_in[4];
  const float* Wv = (const float*)d_in[5];
  const float* bv = (const float*)d_in[6];
  const float* Wo = (const float*)d_in[7];
  const float* bo = (const float*)d_in[8];

  char* ws = (char*)d_ws;
  // Workspace map (bytes): total ~26 MB
  unsigned short* qh  = (unsigned short*)(ws + 0);          // 2 MB
  unsigned short* qlo = (unsigned short*)(ws + 2097152);    // 2 MB
  unsigned short* KVF = (unsigned short*)(ws + 4194304);    // 12 MB fused kh|kl|V frags
  unsigned short* ao  = (unsigned short*)(ws + 16777216);   // 8 MB  [32768][128]
  unsigned short* Wth = (unsigned short*)(ws + 25165824);   // 96 KB [192][256]
  unsigned short* Wtl = (unsigned short*)(ws + 25264128);   // 96 KB
  unsigned short* WoT = (unsigned short*)(ws + 25362432);   // 64 KB [256][128]
  float*          lst = (float*)(ws + 25493504);            // 384 KB [3][32768]
  // O-partials live in d_out used as scratch: [3][32768][128] bf16 = 24 MB,
  // drained by combine_splits before out_proj overwrites d_out.
  unsigned short* opart = (unsigned short*)d_out;

  prep_weights<<<320, 256, 0, stream>>>(Wq, Wk, Wv, Wo, Wth, Wtl, WoT);
  proj_qkv<<<1024, 256, 0, stream>>>(x, Wth, Wtl, bq, bk, bv, qh, qlo, KVF);
  flash_attn<<<768, 256, 0, stream>>>(qh, qlo, KVF, opart, lst);
  combine_splits<<<2048, 256, 0, stream>>>(opart, lst, ao);
  out_proj<<<512, 256, 0, stream>>>(ao, WoT, bo, x, (float*)d_out);
}